// Round 4
// baseline (3297.668 us; speedup 1.0000x reference)
//
#include <hip/hip_runtime.h>

// T=256, B=128, H=2048. M = T*B = 32768.
// ws layout (bytes):
//   XP     @ 0          : 134217728   (xproj, bf16, [t*128+b][h])
//   WT_in  @ 134217728  : 8388608     (w_in^T bf16, [n][k])
//   WT_rec @ 142606336  : 8388608     (w_rec^T bf16, [n][k])
//   hA     @ 150994944  : 524288      (h written at even t)
//   hB     @ 151519232  : 524288      (h written at odd t)
//   BAR    @ 152043520  : 32768       (ready flags 16 KB | consumed flags 16 KB)

typedef __bf16 bf16x8 __attribute__((ext_vector_type(8)));
typedef float f32x4 __attribute__((ext_vector_type(4)));
typedef unsigned long long ullx2 __attribute__((ext_vector_type(2)));

__device__ __forceinline__ unsigned short f32_to_bf16(float f) {
    unsigned int u = __builtin_bit_cast(unsigned int, f);
    u += 0x7FFFu + ((u >> 16) & 1u);   // round-to-nearest-even
    return (unsigned short)(u >> 16);
}
__device__ __forceinline__ float bf16_to_f32(unsigned short s) {
    unsigned int u = ((unsigned int)s) << 16;
    return __builtin_bit_cast(float, u);
}

// ---------------------------------------------------------------------------
// Kernel 1: fp32 (2048x2048, [k][n]) -> bf16 transposed ([n][k]) via LDS tile.
// ---------------------------------------------------------------------------
__global__ __launch_bounds__(256)
void cvt_transpose(const float* __restrict__ W, unsigned short* __restrict__ WT) {
    __shared__ unsigned short tile[64][68];
    const int tid = threadIdx.x;
    const int n0 = (blockIdx.x & 31) * 64;
    const int k0 = (blockIdx.x >> 5) * 64;
    const int rr = tid >> 4;
    const int cc = (tid & 15) * 4;
#pragma unroll
    for (int p = 0; p < 4; ++p) {
        const int k = rr + p * 16;
        const float4 v = *(const float4*)(W + (size_t)(k0 + k) * 2048 + n0 + cc);
        tile[cc + 0][k] = f32_to_bf16(v.x);
        tile[cc + 1][k] = f32_to_bf16(v.y);
        tile[cc + 2][k] = f32_to_bf16(v.z);
        tile[cc + 3][k] = f32_to_bf16(v.w);
    }
    __syncthreads();
#pragma unroll
    for (int p = 0; p < 4; ++p) {
        const int n = rr + p * 16;
        unsigned int lo = (unsigned int)tile[n][cc]     | ((unsigned int)tile[n][cc + 1] << 16);
        unsigned int hi = (unsigned int)tile[n][cc + 2] | ((unsigned int)tile[n][cc + 3] << 16);
        uint2 ov; ov.x = lo; ov.y = hi;
        *(uint2*)(WT + (size_t)(n0 + n) * 2048 + k0 + cc) = ov;
    }
}

// ---------------------------------------------------------------------------
// Kernel 2: xproj GEMM. C[m][n] = sum_k X[m][k] * w_in[k][n], stored bf16.
// 128x128 tile, BK=32, 4 waves each 64x64. grid 4096 x 256.
// ---------------------------------------------------------------------------
__global__ __launch_bounds__(256, 2)
void xproj_gemm(const float* __restrict__ X, const unsigned short* __restrict__ WT,
                unsigned short* __restrict__ XP) {
    __shared__ unsigned short As[128 * 32];
    __shared__ unsigned short Bs[128 * 32];
    const int tid  = threadIdx.x;
    const int bid  = blockIdx.x;
    const int m0   = (bid >> 4) * 128;
    const int n0   = (bid & 15) * 128;
    const int lane = tid & 63;
    const int wave = tid >> 6;
    const int wm   = (wave & 1) * 64;
    const int wn   = (wave >> 1) * 64;
    const int lcol = lane & 15;
    const int quad = lane >> 4;

    const int ar = tid >> 3;
    const int ac = (tid & 7) * 4;
    const int br = tid >> 1;
    const int bc = (tid & 1) * 16;

    f32x4 acc[4][4] = {};

    for (int kk = 0; kk < 2048; kk += 32) {
#pragma unroll
        for (int p = 0; p < 4; ++p) {
            const int r = ar + p * 32;
            const float4 v = *(const float4*)(X + (size_t)(m0 + r) * 2048 + kk + ac);
            unsigned int lo = (unsigned int)f32_to_bf16(v.x) | ((unsigned int)f32_to_bf16(v.y) << 16);
            unsigned int hi = (unsigned int)f32_to_bf16(v.z) | ((unsigned int)f32_to_bf16(v.w) << 16);
            uint2 w; w.x = lo; w.y = hi;
            *(uint2*)(As + r * 32 + ac) = w;
        }
        {
            const unsigned short* g = WT + (size_t)(n0 + br) * 2048 + kk + bc;
            const uint4 v0 = *(const uint4*)(g);
            const uint4 v1 = *(const uint4*)(g + 8);
            *(uint4*)(Bs + br * 32 + bc)     = v0;
            *(uint4*)(Bs + br * 32 + bc + 8) = v1;
        }
        __syncthreads();
        bf16x8 af[4], bf[4];
#pragma unroll
        for (int i = 0; i < 4; ++i)
            af[i] = __builtin_bit_cast(bf16x8, *(const uint4*)(As + (wm + i * 16 + lcol) * 32 + quad * 8));
#pragma unroll
        for (int j = 0; j < 4; ++j)
            bf[j] = __builtin_bit_cast(bf16x8, *(const uint4*)(Bs + (wn + j * 16 + lcol) * 32 + quad * 8));
#pragma unroll
        for (int i = 0; i < 4; ++i)
#pragma unroll
            for (int j = 0; j < 4; ++j)
                acc[i][j] = __builtin_amdgcn_mfma_f32_16x16x32_bf16(af[i], bf[j], acc[i][j], 0, 0, 0);
        __syncthreads();
    }
#pragma unroll
    for (int i = 0; i < 4; ++i)
#pragma unroll
        for (int j = 0; j < 4; ++j) {
            const int row = m0 + wm + i * 16 + quad * 4;
            const int col = n0 + wn + j * 16 + lcol;
#pragma unroll
            for (int r = 0; r < 4; ++r)
                XP[(size_t)(row + r) * 2048 + col] = f32_to_bf16(acc[i][j][r]);
        }
}

// ---------------------------------------------------------------------------
// Kernel 3: persistent recurrence, BARRIER-FREE chunked pipeline.
// Block (nb = bid>>2, bb = bid&3) owns tile [bb*32 batches) x [nb*32 cols).
// Wave w consumes h columns [512w, 512w+512) -> produced by the 16 blocks
// nb in [16w, 16w+16). Per-block flag words (64B apart, relaxed agent,
// sc0/sc1 = L3-coherent, no cache maintenance):
//   ready[bb][nb]    = t+1  : block's h@t stores are drained to L3
//   consumed[bb][nb] = t    : block finished reading h@{t-1} (dist-2 guard)
// Consumer wave polls only its 16 producers; producer polls consumed>=t-1
// before overwriting the t-2 buffer (2 steps of slack -> usually free).
// ---------------------------------------------------------------------------
__global__ __launch_bounds__(256, 1)
void rnn_scan(const unsigned short* __restrict__ XP,
              const unsigned short* __restrict__ WT,
              const float* __restrict__ bias,
              unsigned short* __restrict__ hA,
              unsigned short* __restrict__ hB,
              float* __restrict__ out,
              unsigned int* __restrict__ bar) {
    __shared__ unsigned short Ws[32 * 2056];  // 32 cols x 2048 k, rows padded
    __shared__ float red[4 * 1024];           // 4 wave-partials of 32x32
    const int tid  = threadIdx.x;
    const int bid  = blockIdx.x;
    const int bb   = bid & 3;
    const int nb   = bid >> 2;
    const int n0   = nb * 32;
    const int m0   = bb * 32;
    const int lane = tid & 63;
    const int wave = tid >> 6;
    const int lcol = lane & 15;
    const int quad = lane >> 4;

    // flag pointers (16 uints = 64 B per block slot)
    unsigned int* rdy_own = bar + (bb * 64 + nb) * 16;
    unsigned int* cns_own = bar + 4096 + (bb * 64 + nb) * 16;
    const unsigned int* rdy_poll = bar + (bb * 64 + wave * 16 + lcol) * 16;        // my chunk's producers
    const unsigned int* cns_poll = bar + 4096 + (bb * 64 + lane) * 16;             // all 64 group blocks

    // load w_rec^T slice into LDS
    {
        const int r  = tid >> 3;
        const int ch = (tid & 7) * 256;
        const unsigned short* src = WT + (size_t)(n0 + r) * 2048 + ch;
        unsigned short* dst = Ws + r * 2056 + ch;
#pragma unroll
        for (int c = 0; c < 32; ++c)
            *(uint4*)(dst + c * 8) = *(const uint4*)(src + c * 8);
    }
    const int erow = tid >> 3;
    const int ecol = (tid & 7) * 4;
    const float4 b4 = *(const float4*)(bias + n0 + ecol);
    __syncthreads();

    const int kb = wave * 512;
    for (int t = 0; t < 256; ++t) {
        const uint2 xpu = *(const uint2*)(XP + (size_t)(t * 128 + m0 + erow) * 2048 + n0 + ecol);
        float4 sum = {0.f, 0.f, 0.f, 0.f};
        if (t > 0) {
            // wait for MY chunk's 16 producers to have h@{t-1} at L3
            while (__hip_atomic_load(rdy_poll, __ATOMIC_RELAXED, __HIP_MEMORY_SCOPE_AGENT) < (unsigned)t)
                __builtin_amdgcn_s_sleep(1);
            __builtin_amdgcn_fence(__ATOMIC_ACQUIRE, "workgroup");

            const unsigned short* hprev = (t & 1) ? hA : hB;
            f32x4 a00 = {}, a01 = {}, a10 = {}, a11 = {};
            const unsigned long long* a0p =
                (const unsigned long long*)(hprev + (size_t)(m0 + lcol) * 2048 + kb + quad * 8);
            const unsigned long long* a1p = a0p + 16 * 2048 / 4;   // +16 rows (ULL units)
            const unsigned short* b0p = Ws + lcol * 2056 + kb + quad * 8;
            const unsigned short* b1p = b0p + 16 * 2056;
#pragma unroll
            for (int it = 0; it < 16; ++it) {
                const int ko = it * 8;     // ULL units: 32 bf16 = 8 ULL per iter
                ullx2 u0, u1;
                u0.x = __hip_atomic_load(a0p + ko,     __ATOMIC_RELAXED, __HIP_MEMORY_SCOPE_AGENT);
                u0.y = __hip_atomic_load(a0p + ko + 1, __ATOMIC_RELAXED, __HIP_MEMORY_SCOPE_AGENT);
                u1.x = __hip_atomic_load(a1p + ko,     __ATOMIC_RELAXED, __HIP_MEMORY_SCOPE_AGENT);
                u1.y = __hip_atomic_load(a1p + ko + 1, __ATOMIC_RELAXED, __HIP_MEMORY_SCOPE_AGENT);
                bf16x8 a0 = __builtin_bit_cast(bf16x8, u0);
                bf16x8 a1 = __builtin_bit_cast(bf16x8, u1);
                bf16x8 b0 = __builtin_bit_cast(bf16x8, *(const uint4*)(b0p + it * 32));
                bf16x8 b1 = __builtin_bit_cast(bf16x8, *(const uint4*)(b1p + it * 32));
                a00 = __builtin_amdgcn_mfma_f32_16x16x32_bf16(a0, b0, a00, 0, 0, 0);
                a01 = __builtin_amdgcn_mfma_f32_16x16x32_bf16(a0, b1, a01, 0, 0, 0);
                a10 = __builtin_amdgcn_mfma_f32_16x16x32_bf16(a1, b0, a10, 0, 0, 0);
                a11 = __builtin_amdgcn_mfma_f32_16x16x32_bf16(a1, b1, a11, 0, 0, 0);
            }
            float* rw = red + wave * 1024;
#pragma unroll
            for (int r = 0; r < 4; ++r) {
                rw[(quad * 4 + r) * 32 + lcol]           = a00[r];
                rw[(quad * 4 + r) * 32 + 16 + lcol]      = a01[r];
                rw[(16 + quad * 4 + r) * 32 + lcol]      = a10[r];
                rw[(16 + quad * 4 + r) * 32 + 16 + lcol] = a11[r];
            }
            __syncthreads();   // (A) all waves done loading h@{t-1} + red ready
            if (tid == 0)      // signal: this block finished READING h@{t-1}
                __hip_atomic_store(cns_own, (unsigned)t, __ATOMIC_RELAXED, __HIP_MEMORY_SCOPE_AGENT);
            const float4 s0 = *(const float4*)(red + 0 * 1024 + tid * 4);
            const float4 s1 = *(const float4*)(red + 1 * 1024 + tid * 4);
            const float4 s2 = *(const float4*)(red + 2 * 1024 + tid * 4);
            const float4 s3 = *(const float4*)(red + 3 * 1024 + tid * 4);
            sum.x = (s0.x + s1.x) + (s2.x + s3.x);
            sum.y = (s0.y + s1.y) + (s2.y + s3.y);
            sum.z = (s0.z + s1.z) + (s2.z + s3.z);
            sum.w = (s0.w + s1.w) + (s2.w + s3.w);
        }
        float4 v;
        v.x = tanhf(bf16_to_f32((unsigned short)(xpu.x & 0xFFFFu)) + sum.x + b4.x);
        v.y = tanhf(bf16_to_f32((unsigned short)(xpu.x >> 16))     + sum.y + b4.y);
        v.z = tanhf(bf16_to_f32((unsigned short)(xpu.y & 0xFFFFu)) + sum.z + b4.z);
        v.w = tanhf(bf16_to_f32((unsigned short)(xpu.y >> 16))     + sum.w + b4.w);
        if (t < 255) {
            // dist-2 write-safety: everyone must have READ h@{t-2} (this buffer)
            if (t >= 2) {
                while (__hip_atomic_load(cns_poll, __ATOMIC_RELAXED, __HIP_MEMORY_SCOPE_AGENT) < (unsigned)(t - 1))
                    __builtin_amdgcn_s_sleep(1);
            }
            unsigned short* hc = (t & 1) ? hB : hA;
            unsigned long long pv =
                  (unsigned long long)((unsigned int)f32_to_bf16(v.x) | ((unsigned int)f32_to_bf16(v.y) << 16))
                | ((unsigned long long)((unsigned int)f32_to_bf16(v.z) | ((unsigned int)f32_to_bf16(v.w) << 16)) << 32);
            __hip_atomic_store((unsigned long long*)(hc + (size_t)(m0 + erow) * 2048 + n0 + ecol),
                               pv, __ATOMIC_RELAXED, __HIP_MEMORY_SCOPE_AGENT);
            __builtin_amdgcn_s_waitcnt(0);   // drain: h@t at coherence point
            __syncthreads();                 // (B) whole block drained (guards red reuse)
            if (tid == 0)                    // publish h@t
                __hip_atomic_store(rdy_own, (unsigned)(t + 1), __ATOMIC_RELAXED, __HIP_MEMORY_SCOPE_AGENT);
        } else {
            *(float4*)(out + (size_t)(m0 + erow) * 2048 + n0 + ecol) = v;
        }
    }
}

// ---------------------------------------------------------------------------
extern "C" void kernel_launch(void* const* d_in, const int* in_sizes, int n_in,
                              void* d_out, int out_size, void* d_ws, size_t ws_size,
                              hipStream_t stream) {
    const float* x     = (const float*)d_in[0];
    const float* w_in  = (const float*)d_in[1];
    const float* w_rec = (const float*)d_in[2];
    const float* bias  = (const float*)d_in[3];
    float* out = (float*)d_out;

    char* ws = (char*)d_ws;
    unsigned short* XP     = (unsigned short*)(ws);
    unsigned short* WT_in  = (unsigned short*)(ws + 134217728);
    unsigned short* WT_rec = (unsigned short*)(ws + 134217728 + 8388608);
    unsigned short* hA     = (unsigned short*)(ws + 150994944);
    unsigned short* hB     = (unsigned short*)(ws + 150994944 + 524288);
    unsigned int*   BAR    = (unsigned int*)(ws + 152043520);

    hipMemsetAsync(BAR, 0, 32768, stream);
    cvt_transpose<<<dim3(1024), dim3(256), 0, stream>>>(w_in,  WT_in);
    cvt_transpose<<<dim3(1024), dim3(256), 0, stream>>>(w_rec, WT_rec);
    xproj_gemm<<<dim3(4096), dim3(256), 0, stream>>>(x, WT_in, XP);

    void* args[] = {(void*)&XP, (void*)&WT_rec, (void*)&bias,
                    (void*)&hA, (void*)&hB, (void*)&out, (void*)&BAR};
    hipLaunchCooperativeKernel(reinterpret_cast<void*>(rnn_scan),
                               dim3(256), dim3(256), args, 0, stream);
}

// Round 5
// 2879.659 us; speedup vs baseline: 1.1452x; 1.1452x over previous
//
#include <hip/hip_runtime.h>

// T=256, B=128, H=2048. M = T*B = 32768.
// ws layout (bytes):
//   XP     @ 0          : 134217728   (xproj, bf16, [t*128+b][h])
//   WT_in  @ 134217728  : 8388608     (w_in^T bf16, [n][k])
//   WT_rec @ 142606336  : 8388608     (w_rec^T bf16, [n][k])
//   hA     @ 150994944  : 524288      (h written at even t)
//   hB     @ 151519232  : 524288      (h written at odd t)
//   BAR    @ 152043520  : 32768       (ready flags 16 KB | consumed flags 16 KB)

typedef __bf16 bf16x8 __attribute__((ext_vector_type(8)));
typedef float f32x4 __attribute__((ext_vector_type(4)));

__device__ __forceinline__ unsigned short f32_to_bf16(float f) {
    unsigned int u = __builtin_bit_cast(unsigned int, f);
    u += 0x7FFFu + ((u >> 16) & 1u);   // round-to-nearest-even
    return (unsigned short)(u >> 16);
}
__device__ __forceinline__ float bf16_to_f32(unsigned short s) {
    unsigned int u = ((unsigned int)s) << 16;
    return __builtin_bit_cast(float, u);
}

// ---------------------------------------------------------------------------
// Kernel 1: fp32 (2048x2048, [k][n]) -> bf16 transposed ([n][k]) via LDS tile.
// ---------------------------------------------------------------------------
__global__ __launch_bounds__(256)
void cvt_transpose(const float* __restrict__ W, unsigned short* __restrict__ WT) {
    __shared__ unsigned short tile[64][68];
    const int tid = threadIdx.x;
    const int n0 = (blockIdx.x & 31) * 64;
    const int k0 = (blockIdx.x >> 5) * 64;
    const int rr = tid >> 4;
    const int cc = (tid & 15) * 4;
#pragma unroll
    for (int p = 0; p < 4; ++p) {
        const int k = rr + p * 16;
        const float4 v = *(const float4*)(W + (size_t)(k0 + k) * 2048 + n0 + cc);
        tile[cc + 0][k] = f32_to_bf16(v.x);
        tile[cc + 1][k] = f32_to_bf16(v.y);
        tile[cc + 2][k] = f32_to_bf16(v.z);
        tile[cc + 3][k] = f32_to_bf16(v.w);
    }
    __syncthreads();
#pragma unroll
    for (int p = 0; p < 4; ++p) {
        const int n = rr + p * 16;
        unsigned int lo = (unsigned int)tile[n][cc]     | ((unsigned int)tile[n][cc + 1] << 16);
        unsigned int hi = (unsigned int)tile[n][cc + 2] | ((unsigned int)tile[n][cc + 3] << 16);
        uint2 ov; ov.x = lo; ov.y = hi;
        *(uint2*)(WT + (size_t)(n0 + n) * 2048 + k0 + cc) = ov;
    }
}

// ---------------------------------------------------------------------------
// Kernel 2: xproj GEMM. C[m][n] = sum_k X[m][k] * w_in[k][n], stored bf16.
// 128x128 tile, BK=32, 4 waves each 64x64. grid 4096 x 256.
// ---------------------------------------------------------------------------
__global__ __launch_bounds__(256, 2)
void xproj_gemm(const float* __restrict__ X, const unsigned short* __restrict__ WT,
                unsigned short* __restrict__ XP) {
    __shared__ unsigned short As[128 * 32];
    __shared__ unsigned short Bs[128 * 32];
    const int tid  = threadIdx.x;
    const int bid  = blockIdx.x;
    const int m0   = (bid >> 4) * 128;
    const int n0   = (bid & 15) * 128;
    const int lane = tid & 63;
    const int wave = tid >> 6;
    const int wm   = (wave & 1) * 64;
    const int wn   = (wave >> 1) * 64;
    const int lcol = lane & 15;
    const int quad = lane >> 4;

    const int ar = tid >> 3;
    const int ac = (tid & 7) * 4;
    const int br = tid >> 1;
    const int bc = (tid & 1) * 16;

    f32x4 acc[4][4] = {};

    for (int kk = 0; kk < 2048; kk += 32) {
#pragma unroll
        for (int p = 0; p < 4; ++p) {
            const int r = ar + p * 32;
            const float4 v = *(const float4*)(X + (size_t)(m0 + r) * 2048 + kk + ac);
            unsigned int lo = (unsigned int)f32_to_bf16(v.x) | ((unsigned int)f32_to_bf16(v.y) << 16);
            unsigned int hi = (unsigned int)f32_to_bf16(v.z) | ((unsigned int)f32_to_bf16(v.w) << 16);
            uint2 w; w.x = lo; w.y = hi;
            *(uint2*)(As + r * 32 + ac) = w;
        }
        {
            const unsigned short* g = WT + (size_t)(n0 + br) * 2048 + kk + bc;
            const uint4 v0 = *(const uint4*)(g);
            const uint4 v1 = *(const uint4*)(g + 8);
            *(uint4*)(Bs + br * 32 + bc)     = v0;
            *(uint4*)(Bs + br * 32 + bc + 8) = v1;
        }
        __syncthreads();
        bf16x8 af[4], bf[4];
#pragma unroll
        for (int i = 0; i < 4; ++i)
            af[i] = __builtin_bit_cast(bf16x8, *(const uint4*)(As + (wm + i * 16 + lcol) * 32 + quad * 8));
#pragma unroll
        for (int j = 0; j < 4; ++j)
            bf[j] = __builtin_bit_cast(bf16x8, *(const uint4*)(Bs + (wn + j * 16 + lcol) * 32 + quad * 8));
#pragma unroll
        for (int i = 0; i < 4; ++i)
#pragma unroll
            for (int j = 0; j < 4; ++j)
                acc[i][j] = __builtin_amdgcn_mfma_f32_16x16x32_bf16(af[i], bf[j], acc[i][j], 0, 0, 0);
        __syncthreads();
    }
#pragma unroll
    for (int i = 0; i < 4; ++i)
#pragma unroll
        for (int j = 0; j < 4; ++j) {
            const int row = m0 + wm + i * 16 + quad * 4;
            const int col = n0 + wn + j * 16 + lcol;
#pragma unroll
            for (int r = 0; r < 4; ++r)
                XP[(size_t)(row + r) * 2048 + col] = f32_to_bf16(acc[i][j][r]);
        }
}

// ---------------------------------------------------------------------------
// Kernel 3: persistent recurrence. 256 blocks x 256 threads.
// XCD-affinity: group g = (bid&7)>>1 (each batch group lives on 2 XCDs,
// assuming bid%8 XCD round-robin — perf heuristic only).
// h stores: 8B agent-scope write-through atomics (L2 stays clean).
// h loads:  PLAIN dwordx4 (L2-allocating) — legal because each block issues
// one agent ACQUIRE fence (buffer_inv, flash — no wb walk since L2 has no
// dirty h lines) after its producers are ready and before any h read.
// Flags (relaxed agent atomics, 64B-strided): rdy[g][nb]=t+1 (h@t at L3),
// cns[g][nb]=t (done reading h@{t-1}; dist-2 overwrite guard).
// ---------------------------------------------------------------------------
__global__ __launch_bounds__(256, 1)
void rnn_scan(const unsigned short* __restrict__ XP,
              const unsigned short* __restrict__ WT,
              const float* __restrict__ bias,
              unsigned short* __restrict__ hA,
              unsigned short* __restrict__ hB,
              float* __restrict__ out,
              unsigned int* __restrict__ bar) {
    __shared__ unsigned short Ws[32 * 2056];  // 32 cols x 2048 k, rows padded
    __shared__ float red[4 * 1024];           // 4 wave-partials of 32x32
    const int tid  = threadIdx.x;
    const int bid  = blockIdx.x;
    const int g    = (bid & 7) >> 1;               // batch group (XCD-affine)
    const int nb   = ((bid >> 3) << 1) | (bid & 1);// column block 0..63
    const int n0   = nb * 32;
    const int m0   = g * 32;
    const int lane = tid & 63;
    const int wave = tid >> 6;
    const int lcol = lane & 15;
    const int quad = lane >> 4;

    unsigned int* rdy_own = bar + (g * 64 + nb) * 16;
    unsigned int* cns_own = bar + 4096 + (g * 64 + nb) * 16;
    const unsigned int* rdy_poll = bar + (g * 64 + wave * 16 + lcol) * 16;  // my chunk's producers
    const unsigned int* cns_poll = bar + 4096 + (g * 64 + lane) * 16;       // all 64 group blocks

    // load w_rec^T slice into LDS
    {
        const int r  = tid >> 3;
        const int ch = (tid & 7) * 256;
        const unsigned short* src = WT + (size_t)(n0 + r) * 2048 + ch;
        unsigned short* dst = Ws + r * 2056 + ch;
#pragma unroll
        for (int c = 0; c < 32; ++c)
            *(uint4*)(dst + c * 8) = *(const uint4*)(src + c * 8);
    }
    const int erow = tid >> 3;
    const int ecol = (tid & 7) * 4;
    const float4 b4 = *(const float4*)(bias + n0 + ecol);
    __syncthreads();

    const int kb = wave * 512;
    for (int t = 0; t < 256; ++t) {
        const uint2 xpu = *(const uint2*)(XP + (size_t)(t * 128 + m0 + erow) * 2048 + n0 + ecol);
        float4 sum = {0.f, 0.f, 0.f, 0.f};
        if (t > 0) {
            // wait for MY chunk's 16 producers to have h@{t-1} at L3
            while (__hip_atomic_load(rdy_poll, __ATOMIC_RELAXED, __HIP_MEMORY_SCOPE_AGENT) < (unsigned)t)
                __builtin_amdgcn_s_sleep(1);
            __syncthreads();                       // whole block's producers ready
            if (tid == 0)
                __builtin_amdgcn_fence(__ATOMIC_ACQUIRE, "agent");  // buffer_inv (L1+L2)
            __syncthreads();                       // inv done before any h read

            const unsigned short* hprev = (t & 1) ? hA : hB;
            f32x4 a00 = {}, a01 = {}, a10 = {}, a11 = {};
            const uint4* a0p = (const uint4*)(hprev + (size_t)(m0 + lcol) * 2048 + kb + quad * 8);
            const uint4* a1p = a0p + 16 * 2048 / 8;   // +16 rows in uint4 units
            const unsigned short* b0p = Ws + lcol * 2056 + kb + quad * 8;
            const unsigned short* b1p = b0p + 16 * 2056;
#pragma unroll
            for (int it = 0; it < 16; ++it) {
                bf16x8 a0 = __builtin_bit_cast(bf16x8, a0p[it * 4]);   // plain dwordx4
                bf16x8 a1 = __builtin_bit_cast(bf16x8, a1p[it * 4]);
                bf16x8 b0 = __builtin_bit_cast(bf16x8, *(const uint4*)(b0p + it * 32));
                bf16x8 b1 = __builtin_bit_cast(bf16x8, *(const uint4*)(b1p + it * 32));
                a00 = __builtin_amdgcn_mfma_f32_16x16x32_bf16(a0, b0, a00, 0, 0, 0);
                a01 = __builtin_amdgcn_mfma_f32_16x16x32_bf16(a0, b1, a01, 0, 0, 0);
                a10 = __builtin_amdgcn_mfma_f32_16x16x32_bf16(a1, b0, a10, 0, 0, 0);
                a11 = __builtin_amdgcn_mfma_f32_16x16x32_bf16(a1, b1, a11, 0, 0, 0);
            }
            float* rw = red + wave * 1024;
#pragma unroll
            for (int r = 0; r < 4; ++r) {
                rw[(quad * 4 + r) * 32 + lcol]           = a00[r];
                rw[(quad * 4 + r) * 32 + 16 + lcol]      = a01[r];
                rw[(16 + quad * 4 + r) * 32 + lcol]      = a10[r];
                rw[(16 + quad * 4 + r) * 32 + 16 + lcol] = a11[r];
            }
            __syncthreads();   // (A) all waves done loading h@{t-1} + red ready
            if (tid == 0)      // signal: this block finished READING h@{t-1}
                __hip_atomic_store(cns_own, (unsigned)t, __ATOMIC_RELAXED, __HIP_MEMORY_SCOPE_AGENT);
            const float4 s0 = *(const float4*)(red + 0 * 1024 + tid * 4);
            const float4 s1 = *(const float4*)(red + 1 * 1024 + tid * 4);
            const float4 s2 = *(const float4*)(red + 2 * 1024 + tid * 4);
            const float4 s3 = *(const float4*)(red + 3 * 1024 + tid * 4);
            sum.x = (s0.x + s1.x) + (s2.x + s3.x);
            sum.y = (s0.y + s1.y) + (s2.y + s3.y);
            sum.z = (s0.z + s1.z) + (s2.z + s3.z);
            sum.w = (s0.w + s1.w) + (s2.w + s3.w);
        }
        float4 v;
        v.x = tanhf(bf16_to_f32((unsigned short)(xpu.x & 0xFFFFu)) + sum.x + b4.x);
        v.y = tanhf(bf16_to_f32((unsigned short)(xpu.x >> 16))     + sum.y + b4.y);
        v.z = tanhf(bf16_to_f32((unsigned short)(xpu.y & 0xFFFFu)) + sum.z + b4.z);
        v.w = tanhf(bf16_to_f32((unsigned short)(xpu.y >> 16))     + sum.w + b4.w);
        if (t < 255) {
            // dist-2 write-safety: everyone must have READ h@{t-2} (this buffer)
            if (t >= 2) {
                while (__hip_atomic_load(cns_poll, __ATOMIC_RELAXED, __HIP_MEMORY_SCOPE_AGENT) < (unsigned)(t - 1))
                    __builtin_amdgcn_s_sleep(1);
            }
            unsigned short* hc = (t & 1) ? hB : hA;
            unsigned long long pv =
                  (unsigned long long)((unsigned int)f32_to_bf16(v.x) | ((unsigned int)f32_to_bf16(v.y) << 16))
                | ((unsigned long long)((unsigned int)f32_to_bf16(v.z) | ((unsigned int)f32_to_bf16(v.w) << 16)) << 32);
            __hip_atomic_store((unsigned long long*)(hc + (size_t)(m0 + erow) * 2048 + n0 + ecol),
                               pv, __ATOMIC_RELAXED, __HIP_MEMORY_SCOPE_AGENT);
            __builtin_amdgcn_s_waitcnt(0);   // drain: h@t at coherence point
            __syncthreads();                 // (B) whole block drained (guards red reuse)
            if (tid == 0)                    // publish h@t
                __hip_atomic_store(rdy_own, (unsigned)(t + 1), __ATOMIC_RELAXED, __HIP_MEMORY_SCOPE_AGENT);
        } else {
            *(float4*)(out + (size_t)(m0 + erow) * 2048 + n0 + ecol) = v;
        }
    }
}

// ---------------------------------------------------------------------------
extern "C" void kernel_launch(void* const* d_in, const int* in_sizes, int n_in,
                              void* d_out, int out_size, void* d_ws, size_t ws_size,
                              hipStream_t stream) {
    const float* x     = (const float*)d_in[0];
    const float* w_in  = (const float*)d_in[1];
    const float* w_rec = (const float*)d_in[2];
    const float* bias  = (const float*)d_in[3];
    float* out = (float*)d_out;

    char* ws = (char*)d_ws;
    unsigned short* XP     = (unsigned short*)(ws);
    unsigned short* WT_in  = (unsigned short*)(ws + 134217728);
    unsigned short* WT_rec = (unsigned short*)(ws + 134217728 + 8388608);
    unsigned short* hA     = (unsigned short*)(ws + 150994944);
    unsigned short* hB     = (unsigned short*)(ws + 150994944 + 524288);
    unsigned int*   BAR    = (unsigned int*)(ws + 152043520);

    hipMemsetAsync(BAR, 0, 32768, stream);
    cvt_transpose<<<dim3(1024), dim3(256), 0, stream>>>(w_in,  WT_in);
    cvt_transpose<<<dim3(1024), dim3(256), 0, stream>>>(w_rec, WT_rec);
    xproj_gemm<<<dim3(4096), dim3(256), 0, stream>>>(x, WT_in, XP);

    void* args[] = {(void*)&XP, (void*)&WT_rec, (void*)&bias,
                    (void*)&hA, (void*)&hB, (void*)&out, (void*)&BAR};
    hipLaunchCooperativeKernel(reinterpret_cast<void*>(rnn_scan),
                               dim3(256), dim3(256), args, 0, stream);
}

// Round 6
// 2496.178 us; speedup vs baseline: 1.3211x; 1.1536x over previous
//
#include <hip/hip_runtime.h>

// T=256, B=128, H=2048. M = T*B = 32768.
// ws layout (bytes):
//   XP     @ 0          : 134217728   (xproj, bf16, [t*128+b][h])
//   WT_in  @ 134217728  : 8388608     (w_in^T bf16, [n][k])
//   WT_rec @ 142606336  : 8388608     (w_rec^T bf16, [n][k])
//   hA     @ 150994944  : 524288      (h fragments, even t)
//   hB     @ 151519232  : 524288      (h fragments, odd t)
//   BAR    @ 152043520  : 32768       (ready flags 16 KB | consumed flags 16 KB)
//
// h fragment layout (A-operand-major, mfma 16x16x32):
//   frag f = (g*64 + kb)*2 + half  -> 1 KB block;  within: lane*16B + j*2B
//   element: row = 32g + 16*half + (lane&15), k = 32*kb + 8*(lane>>4) + j
// A consumer wave reads lane-contiguous 16 B per fragment (coalesced).

typedef __bf16 bf16x8 __attribute__((ext_vector_type(8)));
typedef float f32x4 __attribute__((ext_vector_type(4)));
typedef unsigned long long ullx2 __attribute__((ext_vector_type(2)));

__device__ __forceinline__ unsigned short f32_to_bf16(float f) {
    unsigned int u = __builtin_bit_cast(unsigned int, f);
    u += 0x7FFFu + ((u >> 16) & 1u);   // round-to-nearest-even
    return (unsigned short)(u >> 16);
}
__device__ __forceinline__ float bf16_to_f32(unsigned short s) {
    unsigned int u = ((unsigned int)s) << 16;
    return __builtin_bit_cast(float, u);
}

// ---------------------------------------------------------------------------
// Kernel 1: fp32 (2048x2048, [k][n]) -> bf16 transposed ([n][k]) via LDS tile.
// ---------------------------------------------------------------------------
__global__ __launch_bounds__(256)
void cvt_transpose(const float* __restrict__ W, unsigned short* __restrict__ WT) {
    __shared__ unsigned short tile[64][68];
    const int tid = threadIdx.x;
    const int n0 = (blockIdx.x & 31) * 64;
    const int k0 = (blockIdx.x >> 5) * 64;
    const int rr = tid >> 4;
    const int cc = (tid & 15) * 4;
#pragma unroll
    for (int p = 0; p < 4; ++p) {
        const int k = rr + p * 16;
        const float4 v = *(const float4*)(W + (size_t)(k0 + k) * 2048 + n0 + cc);
        tile[cc + 0][k] = f32_to_bf16(v.x);
        tile[cc + 1][k] = f32_to_bf16(v.y);
        tile[cc + 2][k] = f32_to_bf16(v.z);
        tile[cc + 3][k] = f32_to_bf16(v.w);
    }
    __syncthreads();
#pragma unroll
    for (int p = 0; p < 4; ++p) {
        const int n = rr + p * 16;
        unsigned int lo = (unsigned int)tile[n][cc]     | ((unsigned int)tile[n][cc + 1] << 16);
        unsigned int hi = (unsigned int)tile[n][cc + 2] | ((unsigned int)tile[n][cc + 3] << 16);
        uint2 ov; ov.x = lo; ov.y = hi;
        *(uint2*)(WT + (size_t)(n0 + n) * 2048 + k0 + cc) = ov;
    }
}

// ---------------------------------------------------------------------------
// Kernel 2: xproj GEMM. C[m][n] = sum_k X[m][k] * w_in[k][n], stored bf16.
// 128x128 tile, BK=32, 4 waves each 64x64. grid 4096 x 256.
// ---------------------------------------------------------------------------
__global__ __launch_bounds__(256, 2)
void xproj_gemm(const float* __restrict__ X, const unsigned short* __restrict__ WT,
                unsigned short* __restrict__ XP) {
    __shared__ unsigned short As[128 * 32];
    __shared__ unsigned short Bs[128 * 32];
    const int tid  = threadIdx.x;
    const int bid  = blockIdx.x;
    const int m0   = (bid >> 4) * 128;
    const int n0   = (bid & 15) * 128;
    const int lane = tid & 63;
    const int wave = tid >> 6;
    const int wm   = (wave & 1) * 64;
    const int wn   = (wave >> 1) * 64;
    const int lcol = lane & 15;
    const int quad = lane >> 4;

    const int ar = tid >> 3;
    const int ac = (tid & 7) * 4;
    const int br = tid >> 1;
    const int bc = (tid & 1) * 16;

    f32x4 acc[4][4] = {};

    for (int kk = 0; kk < 2048; kk += 32) {
#pragma unroll
        for (int p = 0; p < 4; ++p) {
            const int r = ar + p * 32;
            const float4 v = *(const float4*)(X + (size_t)(m0 + r) * 2048 + kk + ac);
            unsigned int lo = (unsigned int)f32_to_bf16(v.x) | ((unsigned int)f32_to_bf16(v.y) << 16);
            unsigned int hi = (unsigned int)f32_to_bf16(v.z) | ((unsigned int)f32_to_bf16(v.w) << 16);
            uint2 w; w.x = lo; w.y = hi;
            *(uint2*)(As + r * 32 + ac) = w;
        }
        {
            const unsigned short* g = WT + (size_t)(n0 + br) * 2048 + kk + bc;
            const uint4 v0 = *(const uint4*)(g);
            const uint4 v1 = *(const uint4*)(g + 8);
            *(uint4*)(Bs + br * 32 + bc)     = v0;
            *(uint4*)(Bs + br * 32 + bc + 8) = v1;
        }
        __syncthreads();
        bf16x8 af[4], bf[4];
#pragma unroll
        for (int i = 0; i < 4; ++i)
            af[i] = __builtin_bit_cast(bf16x8, *(const uint4*)(As + (wm + i * 16 + lcol) * 32 + quad * 8));
#pragma unroll
        for (int j = 0; j < 4; ++j)
            bf[j] = __builtin_bit_cast(bf16x8, *(const uint4*)(Bs + (wn + j * 16 + lcol) * 32 + quad * 8));
#pragma unroll
        for (int i = 0; i < 4; ++i)
#pragma unroll
            for (int j = 0; j < 4; ++j)
                acc[i][j] = __builtin_amdgcn_mfma_f32_16x16x32_bf16(af[i], bf[j], acc[i][j], 0, 0, 0);
        __syncthreads();
    }
#pragma unroll
    for (int i = 0; i < 4; ++i)
#pragma unroll
        for (int j = 0; j < 4; ++j) {
            const int row = m0 + wm + i * 16 + quad * 4;
            const int col = n0 + wn + j * 16 + lcol;
#pragma unroll
            for (int r = 0; r < 4; ++r)
                XP[(size_t)(row + r) * 2048 + col] = f32_to_bf16(acc[i][j][r]);
        }
}

// ---------------------------------------------------------------------------
// Kernel 3: persistent recurrence, fragment-major h + Ws.
// 256 blocks x 256 threads. g = (bid&7)>>1 (XCD-affine batch group),
// nb = column block 0..63. Wave w consumes kb in [16w,16w+16) -> produced by
// blocks nb=kb. h moves via coalesced 8B relaxed agent atomics (sc0 sc1,
// L3-coherent, no cache maintenance ops at all).
// Ws in LDS is fragment-major -> inner ds_read_b128 is conflict-free.
// Flags: rdy[g][nb]=t+1 (h@t at L3), cns[g][nb]=t (done reading h@{t-1}).
// ---------------------------------------------------------------------------
__global__ __launch_bounds__(256, 1)
void rnn_scan(const unsigned short* __restrict__ XP,
              const unsigned short* __restrict__ WT,
              const float* __restrict__ bias,
              unsigned short* __restrict__ hA,
              unsigned short* __restrict__ hB,
              float* __restrict__ out,
              unsigned int* __restrict__ bar) {
    __shared__ unsigned short Ws[64 * 2 * 512];   // fragment-major, 128 KB
    __shared__ float red[4 * 1024];               // 4 wave-partials of 32x32
    const int tid  = threadIdx.x;
    const int bid  = blockIdx.x;
    const int g    = (bid & 7) >> 1;               // batch group (XCD-affine)
    const int nb   = ((bid >> 3) << 1) | (bid & 1);// column block 0..63
    const int n0   = nb * 32;
    const int m0   = g * 32;
    const int lane = tid & 63;
    const int wave = tid >> 6;
    const int lcol = lane & 15;
    const int quad = lane >> 4;

    unsigned int* rdy_own = bar + (g * 64 + nb) * 16;
    unsigned int* cns_own = bar + 4096 + (g * 64 + nb) * 16;
    const unsigned int* rdy_poll = bar + (g * 64 + wave * 16 + lcol) * 16;  // my chunk's producers
    const unsigned int* cns_poll = bar + 4096 + (g * 64 + lane) * 16;       // all 64 group blocks

    // stage w_rec^T slice into LDS in B-fragment-major layout:
    // frag (kb, half): lane L holds B[n = 16*half + (L&15)][k = 32*kb + 8*(L>>4) + j]
    {
        const int r    = tid >> 3;          // local col n 0..31
        const int half = r >> 4;
        const int lc   = r & 15;
        const int ch   = (tid & 7) * 256;   // k start
        const unsigned short* src = WT + (size_t)(n0 + r) * 2048 + ch;
#pragma unroll
        for (int c = 0; c < 32; ++c) {
            const int k    = ch + c * 8;
            const int kb   = k >> 5;
            const int qd   = (k & 31) >> 3;
            unsigned short* dst = Ws + (kb * 2 + half) * 512 + (qd * 16 + lc) * 8;
            *(uint4*)dst = *(const uint4*)(src + c * 8);
        }
    }
    const int erow = tid >> 3;          // epilogue: 4 elems per thread
    const int ecol = (tid & 7) * 4;
    const float4 b4 = *(const float4*)(bias + n0 + ecol);
    // producer store offset (shorts) into fragment-major h
    const size_t hoff = ((size_t)(g * 64 + nb) * 2 + (erow >> 4)) * 512
                        + (size_t)((ecol >> 3) * 16 + (erow & 15)) * 8 + (ecol & 7);
    // consumer load base (ull units): frags (g, kb=wave*16+it, half)
    const size_t s0 = (size_t)(g * 64 + wave * 16) * 256 + lane * 2;
    __syncthreads();

    for (int t = 0; t < 256; ++t) {
        const uint2 xpu = *(const uint2*)(XP + (size_t)(t * 128 + m0 + erow) * 2048 + n0 + ecol);
        float4 sum = {0.f, 0.f, 0.f, 0.f};
        if (t > 0) {
            // wait for MY chunk's 16 producers to have h@{t-1} at L3
            while (__hip_atomic_load(rdy_poll, __ATOMIC_RELAXED, __HIP_MEMORY_SCOPE_AGENT) < (unsigned)t)
                __builtin_amdgcn_s_sleep(1);
            __builtin_amdgcn_fence(__ATOMIC_ACQUIRE, "workgroup");

            const unsigned long long* hp =
                (const unsigned long long*)((t & 1) ? hA : hB);
            f32x4 a00 = {}, a01 = {}, a10 = {}, a11 = {};
            const unsigned long long* a0p = hp + s0;          // half 0
            const unsigned long long* a1p = hp + s0 + 128;    // half 1
            const unsigned short* b0p = Ws + (wave * 16 * 2) * 512 + lane * 8;  // half 0
            const unsigned short* b1p = b0p + 512;                              // half 1
#pragma unroll
            for (int it = 0; it < 16; ++it) {
                const size_t ao = (size_t)it * 256;
                ullx2 u0, u1;
                u0.x = __hip_atomic_load(a0p + ao,     __ATOMIC_RELAXED, __HIP_MEMORY_SCOPE_AGENT);
                u0.y = __hip_atomic_load(a0p + ao + 1, __ATOMIC_RELAXED, __HIP_MEMORY_SCOPE_AGENT);
                u1.x = __hip_atomic_load(a1p + ao,     __ATOMIC_RELAXED, __HIP_MEMORY_SCOPE_AGENT);
                u1.y = __hip_atomic_load(a1p + ao + 1, __ATOMIC_RELAXED, __HIP_MEMORY_SCOPE_AGENT);
                bf16x8 a0 = __builtin_bit_cast(bf16x8, u0);
                bf16x8 a1 = __builtin_bit_cast(bf16x8, u1);
                bf16x8 b0 = __builtin_bit_cast(bf16x8, *(const uint4*)(b0p + it * 1024));
                bf16x8 b1 = __builtin_bit_cast(bf16x8, *(const uint4*)(b1p + it * 1024));
                a00 = __builtin_amdgcn_mfma_f32_16x16x32_bf16(a0, b0, a00, 0, 0, 0);
                a01 = __builtin_amdgcn_mfma_f32_16x16x32_bf16(a0, b1, a01, 0, 0, 0);
                a10 = __builtin_amdgcn_mfma_f32_16x16x32_bf16(a1, b0, a10, 0, 0, 0);
                a11 = __builtin_amdgcn_mfma_f32_16x16x32_bf16(a1, b1, a11, 0, 0, 0);
            }
            float* rw = red + wave * 1024;
#pragma unroll
            for (int r = 0; r < 4; ++r) {
                rw[(quad * 4 + r) * 32 + lcol]           = a00[r];
                rw[(quad * 4 + r) * 32 + 16 + lcol]      = a01[r];
                rw[(16 + quad * 4 + r) * 32 + lcol]      = a10[r];
                rw[(16 + quad * 4 + r) * 32 + 16 + lcol] = a11[r];
            }
            __syncthreads();   // (A) all waves done loading h@{t-1} + red ready
            if (tid == 0)      // signal: this block finished READING h@{t-1}
                __hip_atomic_store(cns_own, (unsigned)t, __ATOMIC_RELAXED, __HIP_MEMORY_SCOPE_AGENT);
            const float4 s0v = *(const float4*)(red + 0 * 1024 + tid * 4);
            const float4 s1v = *(const float4*)(red + 1 * 1024 + tid * 4);
            const float4 s2v = *(const float4*)(red + 2 * 1024 + tid * 4);
            const float4 s3v = *(const float4*)(red + 3 * 1024 + tid * 4);
            sum.x = (s0v.x + s1v.x) + (s2v.x + s3v.x);
            sum.y = (s0v.y + s1v.y) + (s2v.y + s3v.y);
            sum.z = (s0v.z + s1v.z) + (s2v.z + s3v.z);
            sum.w = (s0v.w + s1v.w) + (s2v.w + s3v.w);
        }
        float4 v;
        v.x = tanhf(bf16_to_f32((unsigned short)(xpu.x & 0xFFFFu)) + sum.x + b4.x);
        v.y = tanhf(bf16_to_f32((unsigned short)(xpu.x >> 16))     + sum.y + b4.y);
        v.z = tanhf(bf16_to_f32((unsigned short)(xpu.y & 0xFFFFu)) + sum.z + b4.z);
        v.w = tanhf(bf16_to_f32((unsigned short)(xpu.y >> 16))     + sum.w + b4.w);
        if (t < 255) {
            // dist-2 write-safety: everyone must have READ h@{t-2} (this buffer)
            if (t >= 2) {
                while (__hip_atomic_load(cns_poll, __ATOMIC_RELAXED, __HIP_MEMORY_SCOPE_AGENT) < (unsigned)(t - 1))
                    __builtin_amdgcn_s_sleep(1);
            }
            unsigned short* hc = (t & 1) ? hB : hA;
            unsigned long long pv =
                  (unsigned long long)((unsigned int)f32_to_bf16(v.x) | ((unsigned int)f32_to_bf16(v.y) << 16))
                | ((unsigned long long)((unsigned int)f32_to_bf16(v.z) | ((unsigned int)f32_to_bf16(v.w) << 16)) << 32);
            __hip_atomic_store((unsigned long long*)(hc + hoff), pv,
                               __ATOMIC_RELAXED, __HIP_MEMORY_SCOPE_AGENT);
            __builtin_amdgcn_s_waitcnt(0);   // drain: h@t at coherence point
            __syncthreads();                 // (B) whole block drained (guards red reuse)
            if (tid == 0)                    // publish h@t
                __hip_atomic_store(rdy_own, (unsigned)(t + 1), __ATOMIC_RELAXED, __HIP_MEMORY_SCOPE_AGENT);
        } else {
            *(float4*)(out + (size_t)(m0 + erow) * 2048 + n0 + ecol) = v;
        }
    }
}

// ---------------------------------------------------------------------------
extern "C" void kernel_launch(void* const* d_in, const int* in_sizes, int n_in,
                              void* d_out, int out_size, void* d_ws, size_t ws_size,
                              hipStream_t stream) {
    const float* x     = (const float*)d_in[0];
    const float* w_in  = (const float*)d_in[1];
    const float* w_rec = (const float*)d_in[2];
    const float* bias  = (const float*)d_in[3];
    float* out = (float*)d_out;

    char* ws = (char*)d_ws;
    unsigned short* XP     = (unsigned short*)(ws);
    unsigned short* WT_in  = (unsigned short*)(ws + 134217728);
    unsigned short* WT_rec = (unsigned short*)(ws + 134217728 + 8388608);
    unsigned short* hA     = (unsigned short*)(ws + 150994944);
    unsigned short* hB     = (unsigned short*)(ws + 150994944 + 524288);
    unsigned int*   BAR    = (unsigned int*)(ws + 152043520);

    hipMemsetAsync(BAR, 0, 32768, stream);
    cvt_transpose<<<dim3(1024), dim3(256), 0, stream>>>(w_in,  WT_in);
    cvt_transpose<<<dim3(1024), dim3(256), 0, stream>>>(w_rec, WT_rec);
    xproj_gemm<<<dim3(4096), dim3(256), 0, stream>>>(x, WT_in, XP);

    void* args[] = {(void*)&XP, (void*)&WT_rec, (void*)&bias,
                    (void*)&hA, (void*)&hB, (void*)&out, (void*)&BAR};
    hipLaunchCooperativeKernel(reinterpret_cast<void*>(rnn_scan),
                               dim3(256), dim3(256), args, 0, stream);
}